// Round 8
// baseline (389.860 us; speedup 1.0000x reference)
//
#include <hip/hip_runtime.h>

// Problem constants: B=2, C=64, H=W=256, KS=3, PAD=1, N=9, O=64
// Inputs NCHW fp32; activations internally NHWC bf16: addr = (h*256+w)*64 + c.
// Contraction index k = n*64 + c (n = 3x3 tap, c = channel).

typedef __attribute__((ext_vector_type(8))) short short8;     // 8 bf16 = 4 VGPRs
typedef __attribute__((ext_vector_type(4))) float float4a;    // MFMA accumulator

// fp32 -> bf16 bits, round-to-nearest-even
static __device__ __forceinline__ unsigned short f2bf(float f) {
    unsigned int u = __builtin_bit_cast(unsigned int, f);
    unsigned int r = u + 0x7FFFu + ((u >> 16) & 1u);
    return (unsigned short)(r >> 16);
}
// low/high bf16 of a dword -> fp32 (hi is a single AND)
static __device__ __forceinline__ float bflo(unsigned int u) {
    return __builtin_bit_cast(float, u << 16);
}
static __device__ __forceinline__ float bfhi(unsigned int u) {
    return __builtin_bit_cast(float, u & 0xffff0000u);
}
// bilinear-combine two packed bf16 channels across 4 corners
static __device__ __forceinline__ unsigned int comb2(unsigned int A, unsigned int B,
                                                     unsigned int C, unsigned int D,
                                                     float4 G) {
    const float lo = G.x * bflo(A) + G.y * bflo(B) + G.z * bflo(C) + G.w * bflo(D);
    const float hi = G.x * bfhi(A) + G.y * bfhi(B) + G.z * bfhi(C) + G.w * bfhi(D);
    return (unsigned int)f2bf(lo) | ((unsigned int)f2bf(hi) << 16);
}

// ---------------------------------------------------------------------------
// One kernel packs all four weight tensors.
// w_conv [o][c][n] -> bf16 [o][k=n*64+c]; w_off [oc][c][n] -> bf16 [32][k], pad 0.
__global__ __launch_bounds__(256) void k_pack_all(const float* __restrict__ w1,
                                                  const float* __restrict__ w2,
                                                  const float* __restrict__ wo1,
                                                  const float* __restrict__ wo2,
                                                  unsigned short* __restrict__ w1b,
                                                  unsigned short* __restrict__ w2b,
                                                  unsigned short* __restrict__ wob1,
                                                  unsigned short* __restrict__ wob2) {
    int i = blockIdx.x * 256 + threadIdx.x;
    if (i < 36864) {
        int o = i / 576, r = i - o * 576, n = r >> 6, c = r & 63;
        w1b[i] = f2bf(w1[o * 576 + c * 9 + n]);
    } else if (i < 73728) {
        int j = i - 36864;
        int o = j / 576, r = j - o * 576, n = r >> 6, c = r & 63;
        w2b[j] = f2bf(w2[o * 576 + c * 9 + n]);
    } else if (i < 92160) {
        int j = i - 73728;
        int oc = j / 576, r = j - oc * 576, n = r >> 6, c = r & 63;
        wob1[j] = (oc < 18) ? f2bf(wo1[oc * 576 + c * 9 + n]) : (unsigned short)0;
    } else if (i < 110592) {
        int j = i - 92160;
        int oc = j / 576, r = j - oc * 576, n = r >> 6, c = r & 63;
        wob2[j] = (oc < 18) ? f2bf(wo2[oc * 576 + c * 9 + n]) : (unsigned short)0;
    }
}

// ---------------------------------------------------------------------------
// NCHW fp32 [64][65536] -> NHWC bf16 [65536][64]; grid (1024, B).
__global__ __launch_bounds__(256) void k_transpose_bf(const float* __restrict__ x,
                                                      unsigned short* __restrict__ xt) {
    __shared__ float tile[64][65];
    const float* xb = x + (size_t)blockIdx.y * 4194304;
    unsigned short* xtb = xt + (size_t)blockIdx.y * 4194304;
    const int p0 = blockIdx.x << 6;
    const int p = threadIdx.x & 63;
    const int c0 = threadIdx.x >> 6;   // 0..3
    #pragma unroll
    for (int i = 0; i < 16; ++i) {
        const int c = (i << 2) + c0;
        tile[p][c] = xb[(c << 16) + p0 + p];
    }
    __syncthreads();
    const int cq = (threadIdx.x & 15) << 2;
    const int pr0 = threadIdx.x >> 4;
    #pragma unroll
    for (int j = 0; j < 4; ++j) {
        const int pr = (j << 4) + pr0;
        ushort4 u;
        u.x = f2bf(tile[pr][cq + 0]); u.y = f2bf(tile[pr][cq + 1]);
        u.z = f2bf(tile[pr][cq + 2]); u.w = f2bf(tile[pr][cq + 3]);
        *(ushort4*)(xtb + ((p0 + pr) << 6) + cq) = u;
    }
}

// ---------------------------------------------------------------------------
// Fused deformable conv layer, bf16 NHWC src. Block = 256 thr = 4 waves.
// 1-D grid 8192, XCD-band swizzled: XCD k (lin%8) owns rows [k*32, k*32+32)
// for both batches -> per-XCD-L2 working set ~1.1 MB (band + weights).
// Stages:
//   2'. offset MFMA, A-fragments DIRECT from global NHWC (no im2col/LDS)
//   A.  geometry: 144 threads -> s_aux[(px*9+n)] = {4 idx, 4 w}
//   3.  bilinear gather (16-B loads) -> s_xoff [16px][576] bf16
//   4.  conv MFMA (A from LDS, B from L2-hot global, 9+9 split chains)
// Tap split for gather: g=0 -> {0,2,4,6,8}; g=1 -> {1,3,5,7,7(dup, benign)}.
#define XSTR 584   // s_xoff row stride (bf16): dword stride 292 = 4 mod 32

__global__ __launch_bounds__(256, 4) void k_fused(const unsigned short* __restrict__ src,
                                                  const unsigned short* __restrict__ wob,
                                                  const float* __restrict__ b_off,
                                                  const unsigned short* __restrict__ wtb,
                                                  const float* __restrict__ addsrc,
                                                  void* __restrict__ out,
                                                  int relu, int nhwc_out) {
    __shared__ unsigned short s_xoff[16 * XSTR];   // 18688 B
    __shared__ int            s_aux[1152];         // 4608 B: geometry, later s_out
    __shared__ float          s_off[16 * 20];      // 1280 B   (total 24576 B)

    // ---- XCD-band swizzle ----
    const int lin = blockIdx.x;          // 0..8191
    const int xcd = lin & 7;
    const int s = lin >> 3;              // 0..1023
    const int b = s >> 9;
    const int h = (xcd << 5) | ((s >> 4) & 31);
    const int w0 = (s & 15) << 4;

    const int tid = threadIdx.x;
    const int lane = tid & 63;
    const int wave = tid >> 6;
    const int quad = lane >> 4;
    const int l16 = lane & 15;

    const int px = tid >> 4;          // pixel 0..15 (gather mapping)
    const int oct = tid & 7;          // channel octet (8 bf16 = 16 B)
    const int g = (tid >> 3) & 1;     // tap group
    const unsigned short* srcb = src + ((size_t)b << 22);   // b*65536*64

    // ========== Stage 2': offset MFMA, A direct from global ==========
    if (wave < 2) {
        float4a acc0 = {0.f, 0.f, 0.f, 0.f};
        float4a acc1 = {0.f, 0.f, 0.f, 0.f};
        const unsigned short* brow = wob + (wave * 16 + l16) * 576 + quad * 8;
        #pragma unroll
        for (int ks = 0; ks < 9; ++ks) {
            #pragma unroll
            for (int half = 0; half < 2; ++half) {
                const int kk = ks + half * 9;
                const int k0 = kk * 32 + quad * 8;
                const int n = k0 >> 6;
                const int c0 = k0 & 63;
                const int row = h + (n / 3) - 1;
                const int col = w0 + l16 + (n % 3) - 1;
                const bool inb = (row >= 0) && (row < 256) && (col >= 0) && (col < 256);
                const int plin = inb ? ((row << 8) + col) : 0;
                short8 a = *(const short8*)(srcb + (plin << 6) + c0);
                if (!inb) { short8 z = {0,0,0,0,0,0,0,0}; a = z; }
                const short8 bb = *(const short8*)(brow + kk * 32);
                if (half == 0)
                    acc0 = __builtin_amdgcn_mfma_f32_16x16x32_bf16(a, bb, acc0, 0, 0, 0);
                else
                    acc1 = __builtin_amdgcn_mfma_f32_16x16x32_bf16(a, bb, acc1, 0, 0, 0);
            }
        }
        const int oc = wave * 16 + l16;
        if (oc < 18) {
            const float bia = b_off[oc];
            #pragma unroll
            for (int r = 0; r < 4; ++r)
                s_off[(quad * 4 + r) * 20 + oc] = acc0[r] + acc1[r] + bia;
        }
    }
    __syncthreads();

    // ====== Phase A: geometry for 144 (px,n) pairs -> s_aux ======
    if (tid < 144) {
        const int pxa = tid / 9;
        const int n = tid - pxa * 9;
        const float ox = s_off[pxa * 20 + n];
        const float oy = s_off[pxa * 20 + 9 + n];
        const float pxx = ox + (float)(h + (n / 3));        // h+1 + (n/3 - 1)
        const float pyy = oy + (float)(w0 + pxa + (n % 3)); // w+1 + (n%3 - 1)
        const float fx = floorf(pxx), fy = floorf(pyy);
        const float qltx = fminf(fmaxf(fx, 0.f), 257.f);
        const float qlty = fminf(fmaxf(fy, 0.f), 257.f);
        const float qrbx = fminf(fmaxf(fx + 1.f, 0.f), 257.f);
        const float qrby = fminf(fmaxf(fy + 1.f, 0.f), 257.f);
        const float pxc = fminf(fmaxf(pxx, 0.f), 257.f);
        const float pyc = fminf(fmaxf(pyy, 0.f), 257.f);
        float glt = (1.f + (qltx - pxc)) * (1.f + (qlty - pyc));
        float grb = (1.f - (qrbx - pxc)) * (1.f - (qrby - pyc));
        float glb = (1.f + (qltx - pxc)) * (1.f - (qrby - pyc));
        float grt = (1.f - (qrbx - pxc)) * (1.f + (qlty - pyc));
        const int ilx = (int)qltx, ily = (int)qlty;
        const int irx = (int)qrbx, iry = (int)qrby;
        const bool b0 = (ilx >= 1) && (ilx <= 256) && (ily >= 1) && (ily <= 256);
        const bool b1 = (irx >= 1) && (irx <= 256) && (iry >= 1) && (iry <= 256);
        const bool b2 = (ilx >= 1) && (ilx <= 256) && (iry >= 1) && (iry <= 256);
        const bool b3 = (irx >= 1) && (irx <= 256) && (ily >= 1) && (ily <= 256);
        const int base = tid << 3;
        int4 li;
        li.x = b0 ? (((ilx - 1) << 8) + (ily - 1)) : 0;
        li.y = b1 ? (((irx - 1) << 8) + (iry - 1)) : 0;
        li.z = b2 ? (((ilx - 1) << 8) + (iry - 1)) : 0;
        li.w = b3 ? (((irx - 1) << 8) + (ily - 1)) : 0;
        *(int4*)(s_aux + base) = li;
        float4 gg;
        gg.x = b0 ? glt : 0.f;
        gg.y = b1 ? grb : 0.f;
        gg.z = b2 ? glb : 0.f;
        gg.w = b3 ? grt : 0.f;
        *(float4*)((float*)s_aux + base + 4) = gg;
    }
    __syncthreads();

    // ====== Stage 3: bilinear gather, straight-line, batched ======
    {
        const int nT[5] = {g ? 1 : 0, g ? 3 : 2, g ? 5 : 4, g ? 7 : 6, g ? 7 : 8};
        int4 L[5]; float4 G[5];
        #pragma unroll
        for (int t = 0; t < 5; ++t) {
            const int base = (px * 9 + nT[t]) << 3;
            L[t] = *(const int4*)(s_aux + base);
            G[t] = *(const float4*)((const float*)s_aux + base + 4);
        }
        // round A: taps 0..2
        uint4 A0, B0, C0, D0, A1, B1, C1, D1, A2, B2, C2, D2;
        A0 = *(const uint4*)(srcb + (L[0].x << 6) + (oct << 3));
        B0 = *(const uint4*)(srcb + (L[0].y << 6) + (oct << 3));
        C0 = *(const uint4*)(srcb + (L[0].z << 6) + (oct << 3));
        D0 = *(const uint4*)(srcb + (L[0].w << 6) + (oct << 3));
        A1 = *(const uint4*)(srcb + (L[1].x << 6) + (oct << 3));
        B1 = *(const uint4*)(srcb + (L[1].y << 6) + (oct << 3));
        C1 = *(const uint4*)(srcb + (L[1].z << 6) + (oct << 3));
        D1 = *(const uint4*)(srcb + (L[1].w << 6) + (oct << 3));
        A2 = *(const uint4*)(srcb + (L[2].x << 6) + (oct << 3));
        B2 = *(const uint4*)(srcb + (L[2].y << 6) + (oct << 3));
        C2 = *(const uint4*)(srcb + (L[2].z << 6) + (oct << 3));
        D2 = *(const uint4*)(srcb + (L[2].w << 6) + (oct << 3));
        {
            uint4 r;
            r.x = comb2(A0.x, B0.x, C0.x, D0.x, G[0]);
            r.y = comb2(A0.y, B0.y, C0.y, D0.y, G[0]);
            r.z = comb2(A0.z, B0.z, C0.z, D0.z, G[0]);
            r.w = comb2(A0.w, B0.w, C0.w, D0.w, G[0]);
            *(uint4*)(s_xoff + px * XSTR + (nT[0] << 6) + (oct << 3)) = r;
            r.x = comb2(A1.x, B1.x, C1.x, D1.x, G[1]);
            r.y = comb2(A1.y, B1.y, C1.y, D1.y, G[1]);
            r.z = comb2(A1.z, B1.z, C1.z, D1.z, G[1]);
            r.w = comb2(A1.w, B1.w, C1.w, D1.w, G[1]);
            *(uint4*)(s_xoff + px * XSTR + (nT[1] << 6) + (oct << 3)) = r;
            r.x = comb2(A2.x, B2.x, C2.x, D2.x, G[2]);
            r.y = comb2(A2.y, B2.y, C2.y, D2.y, G[2]);
            r.z = comb2(A2.z, B2.z, C2.z, D2.z, G[2]);
            r.w = comb2(A2.w, B2.w, C2.w, D2.w, G[2]);
            *(uint4*)(s_xoff + px * XSTR + (nT[2] << 6) + (oct << 3)) = r;
        }
        // round B: taps 3..4
        uint4 A3, B3, C3, D3, A4, B4, C4, D4;
        A3 = *(const uint4*)(srcb + (L[3].x << 6) + (oct << 3));
        B3 = *(const uint4*)(srcb + (L[3].y << 6) + (oct << 3));
        C3 = *(const uint4*)(srcb + (L[3].z << 6) + (oct << 3));
        D3 = *(const uint4*)(srcb + (L[3].w << 6) + (oct << 3));
        A4 = *(const uint4*)(srcb + (L[4].x << 6) + (oct << 3));
        B4 = *(const uint4*)(srcb + (L[4].y << 6) + (oct << 3));
        C4 = *(const uint4*)(srcb + (L[4].z << 6) + (oct << 3));
        D4 = *(const uint4*)(srcb + (L[4].w << 6) + (oct << 3));
        {
            uint4 r;
            r.x = comb2(A3.x, B3.x, C3.x, D3.x, G[3]);
            r.y = comb2(A3.y, B3.y, C3.y, D3.y, G[3]);
            r.z = comb2(A3.z, B3.z, C3.z, D3.z, G[3]);
            r.w = comb2(A3.w, B3.w, C3.w, D3.w, G[3]);
            *(uint4*)(s_xoff + px * XSTR + (nT[3] << 6) + (oct << 3)) = r;
            r.x = comb2(A4.x, B4.x, C4.x, D4.x, G[4]);
            r.y = comb2(A4.y, B4.y, C4.y, D4.y, G[4]);
            r.z = comb2(A4.z, B4.z, C4.z, D4.z, G[4]);
            r.w = comb2(A4.w, B4.w, C4.w, D4.w, G[4]);
            *(uint4*)(s_xoff + px * XSTR + (nT[4] << 6) + (oct << 3)) = r;
        }
    }
    __syncthreads();

    // ============ Stage 4: conv MFMA (A from LDS, B from L2-hot global) ========
    float4a acc0 = {0.f, 0.f, 0.f, 0.f};
    float4a acc1 = {0.f, 0.f, 0.f, 0.f};
    {
        const unsigned short* arow = s_xoff + l16 * XSTR + quad * 8;
        const unsigned short* brow = wtb + (wave * 16 + l16) * 576 + quad * 8;
        #pragma unroll
        for (int ks = 0; ks < 9; ++ks) {
            const short8 a0 = *(const short8*)(arow + ks * 32);
            const short8 b0v = *(const short8*)(brow + ks * 32);
            acc0 = __builtin_amdgcn_mfma_f32_16x16x32_bf16(a0, b0v, acc0, 0, 0, 0);
            const short8 a1 = *(const short8*)(arow + (ks + 9) * 32);
            const short8 b1v = *(const short8*)(brow + (ks + 9) * 32);
            acc1 = __builtin_amdgcn_mfma_f32_16x16x32_bf16(a1, b1v, acc1, 0, 0, 0);
        }
        #pragma unroll
        for (int r = 0; r < 4; ++r) acc0[r] += acc1[r];
    }
    const int o = wave * 16 + l16;
    if (nhwc_out) {
        // D col=o (contiguous in NHWC), row=px=quad*4+r -> bf16 stores
        unsigned short* ob = (unsigned short*)out + ((size_t)b << 22);
        unsigned short* orow = ob + ((((h << 8) + w0) << 6)) + o;
        #pragma unroll
        for (int r = 0; r < 4; ++r) {
            float v = acc0[r];
            if (relu) v = fmaxf(v, 0.f);
            orow[(size_t)((quad * 4 + r) << 6)] = f2bf(v);
        }
    } else {
        // NCHW fp32 path via LDS transpose (s_aux reused; barrier above protects)
        float* s_out = (float*)s_aux;   // 64*17 = 1088 <= 1152 dwords
        #pragma unroll
        for (int r = 0; r < 4; ++r)
            s_out[o * 17 + quad * 4 + r] = acc0[r];
        __syncthreads();
        float* ob = (float*)out + ((size_t)b << 22);
        const float* ab = (addsrc != nullptr) ? (addsrc + ((size_t)b << 22)) : nullptr;
        #pragma unroll
        for (int i = 0; i < 4; ++i) {
            const int idx = tid + (i << 8);    // over 64*16
            const int oo = idx >> 4;
            const int p = idx & 15;
            float v = s_out[oo * 17 + p];
            if (relu) v = fmaxf(v, 0.f);
            const int gidx = (oo << 16) + (h << 8) + w0 + p;
            if (ab != nullptr) v += ab[gidx];
            ob[gidx] = v;
        }
    }
}

// ---------------------------------------------------------------------------
extern "C" void kernel_launch(void* const* d_in, const int* in_sizes, int n_in,
                              void* d_out, int out_size, void* d_ws, size_t ws_size,
                              hipStream_t stream) {
    const float* x      = (const float*)d_in[0];
    const float* w_off1 = (const float*)d_in[1];
    const float* b_off1 = (const float*)d_in[2];
    const float* w1     = (const float*)d_in[3];
    const float* w_off2 = (const float*)d_in[4];
    const float* b_off2 = (const float*)d_in[5];
    const float* w2     = (const float*)d_in[6];
    float* outp = (float*)d_out;

    // workspace: 16 MB xT(bf16) + 16 MB midT(bf16) + packed weights = 32.2 MB
    char* ws = (char*)d_ws;
    unsigned short* xT   = (unsigned short*)ws;                     // 16777216 B
    unsigned short* midT = (unsigned short*)(ws + 16777216);        // 16777216 B
    unsigned short* w1b  = (unsigned short*)(ws + 33554432);                    // 73728
    unsigned short* w2b  = (unsigned short*)(ws + 33554432 + 73728);            // 73728
    unsigned short* wob1 = (unsigned short*)(ws + 33554432 + 2 * 73728);        // 36864
    unsigned short* wob2 = (unsigned short*)(ws + 33554432 + 2 * 73728 + 36864);// 36864

    k_pack_all<<<432, 256, 0, stream>>>(w1, w2, w_off1, w_off2, w1b, w2b, wob1, wob2);

    dim3 gT(1024, 2);
    k_transpose_bf<<<gT, 256, 0, stream>>>(x, xT);

    // layer 1: offsets + deform-conv(x), ReLU -> midT (NHWC bf16)
    k_fused<<<8192, 256, 0, stream>>>(xT, wob1, b_off1, w1b, nullptr, midT, 1, 1);
    // layer 2: offsets + deform-conv(mid), + x residual -> out (NCHW fp32)
    k_fused<<<8192, 256, 0, stream>>>(midT, wob2, b_off2, w2b, x, outp, 0, 0);
}